// Round 1
// 127.761 us; speedup vs baseline: 1.0089x; 1.0089x over previous
//
#include <hip/hip_runtime.h>

// Conv2D 3x3 stride-1 pad-1, C_IN=C_OUT=16, H=W=1024, fp32 in/out.
// Fused implicit-GEMM. v2: software-pipelined 2-tile blocks.
//  - grid 16x32 = 512 blocks = exactly 2 blocks/CU resident (no tail).
//  - each block computes two vertical 64x16 tiles; tile B's global loads are
//    issued into registers BEFORE tile A's compute (T14 async-STAGE split),
//    so B's HBM latency hides under A's MFMA+stores, and A's stores overlap
//    B's reads on the memory pipe.
//  - fp32->bf16 packing via v_cvt_pk_bf16_f32 (HW RNE, 1 inst per 2 floats)
//    instead of ~8 VALU ops of manual round-and-shift.
//  - weights: 2304 coalesced loads -> bf16 LDS table [t=0..19][m=0..15][8]
//    (slots 18,19 zeroed); A-fragments via 5x ds_read_b128.
//  - LDS input tile [row][col][cin16], 32B/pixel, 16B-chunk XOR swizzle
//    phys = c ^ ((c>>3)&7). Single buffer reused A->B (barrier-separated).
//  - compute: 5 full K=32 mfma_f32_16x16x32_bf16 per output row.

#define HH 1024
#define WW 1024
#define CIN 16
#define COUT 16
#define TW 64
#define TH 16
#define NT 2                   // vertical tiles per block
#define LROWS (TH + 2)
#define LCOLS (TW + 2)
#define PIX 16                 // shorts per pixel (32B = 2 chunks)
#define NPIX (LROWS * LCOLS)   // 1188

typedef short v8s __attribute__((ext_vector_type(8)));
typedef float v4f __attribute__((ext_vector_type(4)));
typedef unsigned int u32;

__device__ __forceinline__ unsigned short f32_bf16(float f) {
    union { float f; u32 u; } v;
    v.f = f;
    u32 u = v.u;
    u += 0x7fffu + ((u >> 16) & 1u);  // RNE
    return (unsigned short)(u >> 16);
}

// packed {bf16(hi)<<16 | bf16(lo)}, hardware RNE
__device__ __forceinline__ u32 cvt_pk_bf16(float lo, float hi) {
    u32 r;
    asm("v_cvt_pk_bf16_f32 %0, %1, %2" : "=v"(r) : "v"(lo), "v"(hi));
    return r;
}

__device__ __forceinline__ int swz(int c) { return c ^ ((c >> 3) & 7); }

__global__ __launch_bounds__(256, 2)
void conv3x3_fused(const float* __restrict__ x,
                   const float* __restrict__ wgt,
                   const float* __restrict__ bias,
                   float* __restrict__ out) {
    __shared__ __align__(16) unsigned short sm[NPIX * PIX];   // 38016 B
    __shared__ __align__(16) unsigned short wsm[20 * 16 * 8]; // 5120 B

    const int tid = threadIdx.x;
    const int lane = tid & 63;
    const int wave = tid >> 6;
    const int h0a = blockIdx.y * (TH * NT);
    const int w0 = blockIdx.x * TW;

    // ---- weights: coalesced global -> bf16 LDS table [t][m][8] ----
    // wgt linear e = m*144 + c*9 + kh*3 + kw  (c = half*8 + j)
    if (tid < 32) ((uint4*)(wsm + 18 * 16 * 8))[tid] = make_uint4(0u, 0u, 0u, 0u);
    #pragma unroll
    for (int s = 0; s < 9; ++s) {
        const int e = s * 256 + tid;   // 0..2303
        const int m = e / 144;
        const int rem = e - m * 144;
        const int c = rem / 9;
        const int r9 = rem - c * 9;    // kh*3 + kw
        const int t = r9 * 2 + (c >> 3);
        wsm[(t * 16 + m) * 8 + (c & 7)] = f32_bf16(wgt[e]);
    }

    // ---- staging helpers: body task b (0..287) = (row, 4-px group) ----
    auto load_body = [&](int b, int h0, float4* f4) {
        const int r = b >> 4;
        const int j = b & 15;
        const int gh = h0 - 1 + r;
        if ((unsigned)gh < (unsigned)HH) {
            const float4* src = (const float4*)(x + (size_t)gh * WW + w0) + j;
            #pragma unroll
            for (int c = 0; c < CIN; ++c)
                f4[c] = src[(size_t)c * (HH * WW / 4)];
        } else {
            #pragma unroll
            for (int c = 0; c < CIN; ++c)
                f4[c] = make_float4(0.f, 0.f, 0.f, 0.f);
        }
    };
    auto write_body = [&](int b, const float4* f4) {
        const int r = b >> 4;
        const int j = b & 15;
        const int pbase = r * LCOLS + 1 + 4 * j;   // first of 4 pixels
        #pragma unroll
        for (int k = 0; k < 4; ++k) {
            u32 pk[8];
            #pragma unroll
            for (int i = 0; i < 8; ++i) {
                const float lo = ((const float*)&f4[2 * i])[k];
                const float hi = ((const float*)&f4[2 * i + 1])[k];
                pk[i] = cvt_pk_bf16(lo, hi);
            }
            #pragma unroll
            for (int half = 0; half < 2; ++half) {
                const int cc = 2 * pbase + 2 * k + half;
                *(uint4*)(sm + swz(cc) * 8) = *(uint4*)&pk[half * 4];
            }
        }
    };
    // ---- halo task h (0..35): r = h>>1, side = h&1 (1 px, 16 ch scalar) ----
    auto load_halo = [&](int h, int h0, float* f) {
        const int r = h >> 1;
        const int side = h & 1;
        const int gh = h0 - 1 + r;
        const int gw = side ? (w0 + TW) : (w0 - 1);
        if ((unsigned)gh < (unsigned)HH && (unsigned)gw < (unsigned)WW) {
            const float* src = x + (size_t)gh * WW + gw;
            #pragma unroll
            for (int c = 0; c < CIN; ++c) f[c] = src[(size_t)c * (HH * WW)];
        } else {
            #pragma unroll
            for (int c = 0; c < CIN; ++c) f[c] = 0.f;
        }
    };
    auto write_halo = [&](int h, const float* f) {
        const int r = h >> 1;
        const int side = h & 1;
        const int p = r * LCOLS + (side ? 65 : 0);
        u32 pk[8];
        #pragma unroll
        for (int i = 0; i < 8; ++i)
            pk[i] = cvt_pk_bf16(f[2 * i], f[2 * i + 1]);
        #pragma unroll
        for (int half = 0; half < 2; ++half) {
            const int cc = 2 * p + half;
            *(uint4*)(sm + swz(cc) * 8) = *(uint4*)&pk[half * 4];
        }
    };

    // ---- stage tile A (loads first, then pack+write, for latency overlap) ----
    {
        float4 f1[16];
        float4 f2[16];
        float fh[16];
        load_body(tid, h0a, f1);
        if (tid < 32) load_body(256 + tid, h0a, f2);
        else if (tid < 68) load_halo(tid - 32, h0a, fh);
        write_body(tid, f1);
        if (tid < 32) write_body(256 + tid, f2);
        else if (tid < 68) write_halo(tid - 32, fh);
    }

    const int m = lane & 15;       // c_out row of A == pixel index n of B/D
    const int q = lane >> 4;       // quad: supplies k = 8q..8q+7 of each MFMA
    const int colbase = wave * 16 + m;

    // ---- B-chunk offsets: chunk t = 4g+q, t<=17 -> (kh,kw,half) ----
    int Kofs[5];
    #pragma unroll
    for (int g5 = 0; g5 < 5; ++g5) {
        int t = 4 * g5 + q;
        int tt = t > 17 ? 17 : t;      // dead lanes use a harmless valid addr
        int khkw = tt >> 1;
        int kh = khkw / 3;
        int kw = khkw - 3 * kh;
        int half = tt & 1;
        Kofs[g5] = (kh * LCOLS + colbase + kw) * 2 + half;
    }
    float bl[4];
    #pragma unroll
    for (int i = 0; i < 4; ++i) bl[i] = bias[q * 4 + i];

    __syncthreads();

    // ---- prefetch tile B into registers (T14: issue early, write late) ----
    float4 p1[16];
    float4 p2[16];
    float ph[16];
    load_body(tid, h0a + TH, p1);
    if (tid < 32) load_body(256 + tid, h0a + TH, p2);
    else if (tid < 68) load_halo(tid - 32, h0a + TH, ph);

    // ---- A fragments from the LDS weight table (slots 18,19 are zero) ----
    v8s a[5];
    #pragma unroll
    for (int g5 = 0; g5 < 5; ++g5) {
        const int t = 4 * g5 + q;     // 0..19
        a[g5] = *(const v8s*)(wsm + (t * 16 + m) * 8);
    }

    // ---- compute: wave = 16-pixel column group, loop TH rows ----
    auto compute_tile = [&](int h0) {
        #pragma unroll 4
        for (int r = 0; r < TH; ++r) {
            v4f acc = {0.f, 0.f, 0.f, 0.f};
            #pragma unroll
            for (int g5 = 0; g5 < 5; ++g5) {
                const int c = r * (LCOLS * 2) + Kofs[g5];  // logical chunk
                v8s b = *(const v8s*)(sm + swz(c) * 8);
                acc = __builtin_amdgcn_mfma_f32_16x16x32_bf16(a[g5], b, acc, 0, 0, 0);
            }
            float* op = out + (size_t)(h0 + r) * WW + (w0 + colbase);
            #pragma unroll
            for (int i = 0; i < 4; ++i)
                op[(size_t)(q * 4 + i) * (HH * WW)] = acc[i] + bl[i];
        }
    };

    compute_tile(h0a);                 // tile B loads in flight underneath

    __syncthreads();                   // all LDS reads of tile A retired

    // ---- write tile B to LDS (loads have long since landed) ----
    write_body(tid, p1);
    if (tid < 32) write_body(256 + tid, p2);
    else if (tid < 68) write_halo(tid - 32, ph);

    __syncthreads();

    compute_tile(h0a + TH);
}

extern "C" void kernel_launch(void* const* d_in, const int* in_sizes, int n_in,
                              void* d_out, int out_size, void* d_ws, size_t ws_size,
                              hipStream_t stream) {
    const float* x = (const float*)d_in[0];
    const float* w = (const float*)d_in[1];
    const float* b = (const float*)d_in[2];
    float* out = (float*)d_out;
    dim3 grid(WW / TW, HH / (TH * NT));
    conv3x3_fused<<<grid, dim3(256), 0, stream>>>(x, w, b, out);
}

// Round 2
// 126.270 us; speedup vs baseline: 1.0208x; 1.0118x over previous
//
#include <hip/hip_runtime.h>

// Conv2D 3x3 stride-1 pad-1, C_IN=C_OUT=16, H=W=1024, fp32 in/out.
// Fused implicit-GEMM. v3: 4-deep software pipeline, double-buffered LDS.
//  - grid 16x16 = 256 blocks of 512 threads = exactly 1 block/CU (8 waves/CU,
//    2/SIMD). Each block computes four vertical 64x16 tiles.
//  - steady state per tile: [issue loads t+1 -> regs] [compute t from
//    buf[t&1]] [pack+ds_write t+1 -> buf[(t+1)&1]] [barrier]. One barrier
//    per tile; writes never wait on compute readers (other LDS half).
//    3 of 4 compute phases run with HBM reads in flight; output stores
//    overlap next-tile reads on the memory pipe.
//  - fp32->bf16 via v_cvt_pk_bf16_f32 (HW RNE).
//  - weights: 2304 coalesced loads -> bf16 LDS table [t=0..19][m=0..15][8]
//    (slots 18,19 zeroed); A-fragments via 5x ds_read_b128.
//  - LDS input tile [row][col][cin16], 32B/pixel, 16B-chunk XOR swizzle
//    phys = c ^ ((c>>3)&7); two 38016B halves (half-stride is bank-neutral:
//    38016 % 128 == 0).
//  - compute: each wave owns 16 cols x 8 rows; 5 full K=32
//    mfma_f32_16x16x32_bf16 per output row.

#define HH 1024
#define WW 1024
#define CIN 16
#define COUT 16
#define TW 64
#define TH 16
#define NT 4                   // vertical tiles per block
#define LROWS (TH + 2)
#define LCOLS (TW + 2)
#define PIX 16                 // shorts per pixel (32B = 2 chunks)
#define NPIX (LROWS * LCOLS)   // 1188
#define SMHALF (NPIX * PIX)    // 19008 shorts = 38016 B per buffer

typedef short v8s __attribute__((ext_vector_type(8)));
typedef float v4f __attribute__((ext_vector_type(4)));
typedef unsigned int u32;

__device__ __forceinline__ unsigned short f32_bf16(float f) {
    union { float f; u32 u; } v;
    v.f = f;
    u32 u = v.u;
    u += 0x7fffu + ((u >> 16) & 1u);  // RNE
    return (unsigned short)(u >> 16);
}

// packed {bf16(hi)<<16 | bf16(lo)}, hardware RNE
__device__ __forceinline__ u32 cvt_pk_bf16(float lo, float hi) {
    u32 r;
    asm("v_cvt_pk_bf16_f32 %0, %1, %2" : "=v"(r) : "v"(lo), "v"(hi));
    return r;
}

__device__ __forceinline__ int swz(int c) { return c ^ ((c >> 3) & 7); }

__global__ __launch_bounds__(512, 1)
void conv3x3_fused(const float* __restrict__ x,
                   const float* __restrict__ wgt,
                   const float* __restrict__ bias,
                   float* __restrict__ out) {
    __shared__ __align__(16) unsigned short sm[2 * SMHALF];   // 76032 B
    __shared__ __align__(16) unsigned short wsm[20 * 16 * 8]; // 5120 B

    const int tid = threadIdx.x;
    const int lane = tid & 63;
    const int wave = tid >> 6;
    const int h0blk = blockIdx.y * (TH * NT);
    const int w0 = blockIdx.x * TW;

    // ---- weights: coalesced global -> bf16 LDS table [t][m][8] ----
    // wgt linear e = m*144 + c*9 + kh*3 + kw  (c = half*8 + j)
    if (tid < 32) ((uint4*)(wsm + 18 * 16 * 8))[tid] = make_uint4(0u, 0u, 0u, 0u);
    #pragma unroll
    for (int s = 0; s < 5; ++s) {
        const int e = s * 512 + tid;   // 0..2303
        if (e < 2304) {
            const int m = e / 144;
            const int rem = e - m * 144;
            const int c = rem / 9;
            const int r9 = rem - c * 9;    // kh*3 + kw
            const int t = r9 * 2 + (c >> 3);
            wsm[(t * 16 + m) * 8 + (c & 7)] = f32_bf16(wgt[e]);
        }
    }

    // ---- staging: one sweep of 512 threads covers 288 body + 36 halo ----
    // body task tid<288: r = tid>>4 (0..17), 4-px group j = tid&15
    // halo task tid in [288,324): r = (tid-288)>>1, side = (tid-288)&1
    auto load_tile = [&](int t, float4* f4, float* fh) {
        const int h0 = h0blk + t * TH;
        if (tid < 288) {
            const int r = tid >> 4;
            const int j = tid & 15;
            const int gh = h0 - 1 + r;
            if ((unsigned)gh < (unsigned)HH) {
                const float4* src = (const float4*)(x + (size_t)gh * WW + w0) + j;
                #pragma unroll
                for (int c = 0; c < CIN; ++c)
                    f4[c] = src[(size_t)c * (HH * WW / 4)];
            } else {
                #pragma unroll
                for (int c = 0; c < CIN; ++c)
                    f4[c] = make_float4(0.f, 0.f, 0.f, 0.f);
            }
        } else if (tid < 324) {
            const int h = tid - 288;
            const int r = h >> 1;
            const int side = h & 1;
            const int gh = h0 - 1 + r;
            const int gw = side ? (w0 + TW) : (w0 - 1);
            if ((unsigned)gh < (unsigned)HH && (unsigned)gw < (unsigned)WW) {
                const float* src = x + (size_t)gh * WW + gw;
                #pragma unroll
                for (int c = 0; c < CIN; ++c) fh[c] = src[(size_t)c * (HH * WW)];
            } else {
                #pragma unroll
                for (int c = 0; c < CIN; ++c) fh[c] = 0.f;
            }
        }
    };
    auto write_tile = [&](int t, const float4* f4, const float* fh) {
        unsigned short* smb = sm + (t & 1) * SMHALF;
        if (tid < 288) {
            const int r = tid >> 4;
            const int j = tid & 15;
            const int pbase = r * LCOLS + 1 + 4 * j;   // first of 4 pixels
            #pragma unroll
            for (int k = 0; k < 4; ++k) {
                u32 pk[8];
                #pragma unroll
                for (int i = 0; i < 8; ++i) {
                    const float lo = ((const float*)&f4[2 * i])[k];
                    const float hi = ((const float*)&f4[2 * i + 1])[k];
                    pk[i] = cvt_pk_bf16(lo, hi);
                }
                #pragma unroll
                for (int half = 0; half < 2; ++half) {
                    const int cc = 2 * pbase + 2 * k + half;
                    *(uint4*)(smb + swz(cc) * 8) = *(uint4*)&pk[half * 4];
                }
            }
        } else if (tid < 324) {
            const int h = tid - 288;
            const int r = h >> 1;
            const int side = h & 1;
            const int p = r * LCOLS + (side ? 65 : 0);
            u32 pk[8];
            #pragma unroll
            for (int i = 0; i < 8; ++i)
                pk[i] = cvt_pk_bf16(fh[2 * i], fh[2 * i + 1]);
            #pragma unroll
            for (int half = 0; half < 2; ++half) {
                const int cc = 2 * p + half;
                *(uint4*)(smb + swz(cc) * 8) = *(uint4*)&pk[half * 4];
            }
        }
    };

    const int m = lane & 15;       // c_out row of A == pixel index n of B/D
    const int q = lane >> 4;       // quad: supplies k = 8q..8q+7 of each MFMA
    const int wc = wave & 3;       // column group
    const int wq = wave >> 2;      // row half: rows 8*wq .. 8*wq+7
    const int colbase = wc * 16 + m;

    // ---- B-chunk offsets: chunk t = 4g+q, t<=17 -> (kh,kw,half) ----
    int Kofs[5];
    #pragma unroll
    for (int g5 = 0; g5 < 5; ++g5) {
        int t = 4 * g5 + q;
        int tt = t > 17 ? 17 : t;      // dead lanes use a harmless valid addr
        int khkw = tt >> 1;
        int kh = khkw / 3;
        int kw = khkw - 3 * kh;
        int half = tt & 1;
        Kofs[g5] = (kh * LCOLS + colbase + kw) * 2 + half;
    }
    float bl[4];
    #pragma unroll
    for (int i = 0; i < 4; ++i) bl[i] = bias[q * 4 + i];

    // ---- prologue: stage tile 0 ----
    float4 fA[CIN]; float hA[CIN];
    float4 fB[CIN]; float hB[CIN];
    load_tile(0, fA, hA);
    write_tile(0, fA, hA);
    __syncthreads();

    // ---- A fragments from the LDS weight table (slots 18,19 are zero) ----
    v8s a[5];
    #pragma unroll
    for (int g5 = 0; g5 < 5; ++g5) {
        const int t = 4 * g5 + q;     // 0..19
        a[g5] = *(const v8s*)(wsm + (t * 16 + m) * 8);
    }

    // ---- compute: wave = 16 cols x 8 rows ----
    auto compute_tile = [&](int t) {
        const unsigned short* smb = sm + (t & 1) * SMHALF;
        const int h0 = h0blk + t * TH;
        #pragma unroll 4
        for (int rr = 0; rr < 8; ++rr) {
            const int r = wq * 8 + rr;
            v4f acc = {0.f, 0.f, 0.f, 0.f};
            #pragma unroll
            for (int g5 = 0; g5 < 5; ++g5) {
                const int c = r * (LCOLS * 2) + Kofs[g5];  // logical chunk
                v8s b = *(const v8s*)(smb + swz(c) * 8);
                acc = __builtin_amdgcn_mfma_f32_16x16x32_bf16(a[g5], b, acc, 0, 0, 0);
            }
            float* op = out + (size_t)(h0 + r) * WW + (w0 + colbase);
            #pragma unroll
            for (int i = 0; i < 4; ++i)
                op[(size_t)(q * 4 + i) * (HH * WW)] = acc[i] + bl[i];
        }
    };

    // ---- 4-deep pipeline, one barrier per tile ----
    // iter t: loads(t+1) in flight under compute(t); write(t+1) targets the
    // other LDS half so it never waits on compute(t)'s readers. The end-of-
    // iter barrier guarantees no wave can be a full buffer cycle ahead.
    load_tile(1, fB, hB);
    compute_tile(0);
    write_tile(1, fB, hB);
    __syncthreads();

    load_tile(2, fA, hA);
    compute_tile(1);
    write_tile(2, fA, hA);
    __syncthreads();

    load_tile(3, fB, hB);
    compute_tile(2);
    write_tile(3, fB, hB);
    __syncthreads();

    compute_tile(3);
}

extern "C" void kernel_launch(void* const* d_in, const int* in_sizes, int n_in,
                              void* d_out, int out_size, void* d_ws, size_t ws_size,
                              hipStream_t stream) {
    const float* x = (const float*)d_in[0];
    const float* w = (const float*)d_in[1];
    const float* b = (const float*)d_in[2];
    float* out = (float*)d_out;
    dim3 grid(WW / TW, HH / (TH * NT));
    conv3x3_fused<<<grid, dim3(512), 0, stream>>>(x, w, b, out);
}